// Round 2
// baseline (11558.471 us; speedup 1.0000x reference)
//
#include <hip/hip_runtime.h>
#include <cstddef>
#include <cstdint>

#define B_  256
#define T_  512
#define D_  128
#define H_  256
#define G3_ 768
#define C_  10

__device__ __forceinline__ float sigmoid_f(float x) {
    return 1.0f / (1.0f + __expf(-x));
}
__device__ __forceinline__ float tanh_f(float x) {
    return 1.0f - 2.0f / (__expf(2.0f * x) + 1.0f);
}

// ---------------------------------------------------------------------------
// Transpose Whh[3H][H] -> Wt[k][j][3]: scan inner loop reads r,z,n adjacent.
// ---------------------------------------------------------------------------
__global__ void k_transpose_whh(const float* __restrict__ Whh, float* __restrict__ Wt) {
    int j = blockIdx.x;
    int k = threadIdx.x;
    float r = Whh[(size_t)(0 * H_ + j) * H_ + k];
    float z = Whh[(size_t)(1 * H_ + j) * H_ + k];
    float n = Whh[(size_t)(2 * H_ + j) * H_ + k];
    float* p = &Wt[((size_t)k * H_ + j) * 3];
    p[0] = r; p[1] = z; p[2] = n;
}

// ---------------------------------------------------------------------------
// C[M,N] = A[M,K] @ W[N,K]^T + bias[N]  (fp32 NT). Rows of A live in a
// chunked layout: global row m -> batch b = m>>tcShift, tl = m&(Tc-1),
// address = A + b*Abstride + tl*K. C is plain chunk-major [M][N].
// Tile 128(M) x 64(N), BK=16, 256 thr, 8x4 per thread. M%128==0, N%64, K%16.
// ---------------------------------------------------------------------------
__global__ __launch_bounds__(256, 2) void k_gemm_nt_bias(
    const float* __restrict__ A, long Abstride,
    const float* __restrict__ W,
    const float* __restrict__ bias, float* __restrict__ C,
    int N, int K, int tcShift)
{
    __shared__ float As[16][128];
    __shared__ float Ws[16][64];
    const int tid = threadIdx.x;
    const int tx = tid & 15;
    const int ty = tid >> 4;
    const int m0 = blockIdx.y * 128;
    const int n0 = blockIdx.x * 64;
    const int arow = tid >> 1;          // 0..127
    const int ak   = (tid & 1) * 8;     // 0 or 8
    const int wrow = tid >> 2;          // 0..63
    const int wk   = (tid & 3) * 4;     // 0,4,8,12

    const int mask = (1 << tcShift) - 1;
    const int mg = m0 + arow;
    const float* Arow = A + (size_t)(mg >> tcShift) * Abstride + (size_t)(mg & mask) * K;
    const float* Wrow = W + (size_t)(n0 + wrow) * K;

    float acc[8][4] = {};

    for (int k0 = 0; k0 < K; k0 += 16) {
        float4 a0 = *(const float4*)&Arow[k0 + ak];
        float4 a1 = *(const float4*)&Arow[k0 + ak + 4];
        float4 wv = *(const float4*)&Wrow[k0 + wk];
        __syncthreads();
        As[ak + 0][arow] = a0.x; As[ak + 1][arow] = a0.y;
        As[ak + 2][arow] = a0.z; As[ak + 3][arow] = a0.w;
        As[ak + 4][arow] = a1.x; As[ak + 5][arow] = a1.y;
        As[ak + 6][arow] = a1.z; As[ak + 7][arow] = a1.w;
        Ws[wk + 0][wrow] = wv.x; Ws[wk + 1][wrow] = wv.y;
        Ws[wk + 2][wrow] = wv.z; Ws[wk + 3][wrow] = wv.w;
        __syncthreads();
#pragma unroll
        for (int kk = 0; kk < 16; kk++) {
            float a8[8], b4[4];
            *(float4*)&a8[0] = *(const float4*)&As[kk][ty * 8];
            *(float4*)&a8[4] = *(const float4*)&As[kk][ty * 8 + 4];
            *(float4*)&b4[0] = *(const float4*)&Ws[kk][tx * 4];
#pragma unroll
            for (int ii = 0; ii < 8; ii++)
#pragma unroll
                for (int jj = 0; jj < 4; jj++)
                    acc[ii][jj] = fmaf(a8[ii], b4[jj], acc[ii][jj]);
        }
    }

    float b4[4];
#pragma unroll
    for (int jj = 0; jj < 4; jj++) b4[jj] = bias[n0 + tx * 4 + jj];
#pragma unroll
    for (int ii = 0; ii < 8; ii++) {
        float4 v;
        v.x = acc[ii][0] + b4[0];
        v.y = acc[ii][1] + b4[1];
        v.z = acc[ii][2] + b4[2];
        v.w = acc[ii][3] + b4[3];
        *(float4*)&C[(size_t)(m0 + ty * 8 + ii) * N + n0 + tx * 4] = v;
    }
}

// ---------------------------------------------------------------------------
// GRU scan over one T-chunk. 64 blocks x 256 thr; block owns 4 batch rows,
// h[4][256] in LDS; Whh (Wt layout [k][j][3]) streamed from L2 per step.
// h_state[B,H] carries the recurrence across chunk launches.
// gi / out_seq are chunk-major: row (b*Tc + t).
// ---------------------------------------------------------------------------
__global__ __launch_bounds__(256, 1) void k_gru_scan_chunk(
    const float* __restrict__ gi,     // [B*Tc][3H] (bih already added)
    const float* __restrict__ Wt,     // [256][256][3]
    const float* __restrict__ bhh,    // [768]
    float* __restrict__ h_state,      // [B][H] in/out
    float* __restrict__ out_seq,      // [B*Tc][H] or nullptr
    int Tc, int initZero)
{
    __shared__ float hbuf[4][H_];
    const int j  = threadIdx.x;
    const int b0 = blockIdx.x * 4;

    const float br = bhh[j];
    const float bz = bhh[H_ + j];
    const float bn = bhh[2 * H_ + j];

#pragma unroll
    for (int bb = 0; bb < 4; bb++)
        hbuf[bb][j] = initZero ? 0.0f : h_state[(size_t)(b0 + bb) * H_ + j];
    __syncthreads();

    for (int t = 0; t < Tc; ++t) {
        float gr[4], gz[4], gn[4];
#pragma unroll
        for (int bb = 0; bb < 4; bb++) {
            const float* g = gi + ((size_t)(b0 + bb) * Tc + t) * G3_;
            gr[bb] = g[j];
            gz[bb] = g[H_ + j];
            gn[bb] = g[2 * H_ + j];
        }

        float ar[4] = {}, az[4] = {}, an[4] = {};
#pragma unroll 2
        for (int k0 = 0; k0 < H_; k0 += 4) {
            float ha[4][4];
#pragma unroll
            for (int bb = 0; bb < 4; bb++)
                *(float4*)ha[bb] = *(const float4*)&hbuf[bb][k0];
#pragma unroll
            for (int u = 0; u < 4; u++) {
                const float* w = &Wt[((size_t)(k0 + u) * H_ + j) * 3];
                float wr = w[0], wz = w[1], wn = w[2];
#pragma unroll
                for (int bb = 0; bb < 4; bb++) {
                    ar[bb] = fmaf(wr, ha[bb][u], ar[bb]);
                    az[bb] = fmaf(wz, ha[bb][u], az[bb]);
                    an[bb] = fmaf(wn, ha[bb][u], an[bb]);
                }
            }
        }

        float hn[4];
#pragma unroll
        for (int bb = 0; bb < 4; bb++) {
            float r   = sigmoid_f(gr[bb] + ar[bb] + br);
            float z   = sigmoid_f(gz[bb] + az[bb] + bz);
            float ghn = an[bb] + bn;                // bhh_n inside the r-gate
            float n   = tanh_f(gn[bb] + r * ghn);
            hn[bb] = (1.0f - z) * n + z * hbuf[bb][j];
        }

        __syncthreads();   // all readers of hbuf done
#pragma unroll
        for (int bb = 0; bb < 4; bb++) hbuf[bb][j] = hn[bb];

        if (out_seq) {
#pragma unroll
            for (int bb = 0; bb < 4; bb++)
                out_seq[((size_t)(b0 + bb) * Tc + t) * H_ + j] = hn[bb];
        }
        if (t == Tc - 1) {
#pragma unroll
            for (int bb = 0; bb < 4; bb++)
                h_state[(size_t)(b0 + bb) * H_ + j] = hn[bb];
        }
        __syncthreads();   // updates visible before next step
    }
}

// ---------------------------------------------------------------------------
__global__ void k_fc(const float* __restrict__ h, const float* __restrict__ Wfc,
                     const float* __restrict__ bfc, float* __restrict__ out)
{
    int idx = blockIdx.x * blockDim.x + threadIdx.x;
    if (idx >= B_ * C_) return;
    int b = idx / C_, c = idx % C_;
    const float* hp = h + (size_t)b * H_;
    const float* wp = Wfc + (size_t)c * H_;
    float s = bfc[c];
#pragma unroll 4
    for (int k = 0; k < H_; k++) s = fmaf(hp[k], wp[k], s);
    out[idx] = s;
}

// ---------------------------------------------------------------------------
extern "C" void kernel_launch(void* const* d_in, const int* in_sizes, int n_in,
                              void* d_out, int out_size, void* d_ws, size_t ws_size,
                              hipStream_t stream)
{
    const float* x    = (const float*)d_in[0];
    const float* Wih0 = (const float*)d_in[1];
    const float* Whh0 = (const float*)d_in[2];
    const float* bih0 = (const float*)d_in[3];
    const float* bhh0 = (const float*)d_in[4];
    const float* Wih1 = (const float*)d_in[5];
    const float* Whh1 = (const float*)d_in[6];
    const float* bih1 = (const float*)d_in[7];
    const float* bhh1 = (const float*)d_in[8];
    const float* Wfc  = (const float*)d_in[9];
    const float* bfc  = (const float*)d_in[10];
    float* out = (float*)d_out;

    // ---- pick the largest power-of-two T-chunk that fits ws_size ----------
    const size_t fixedB = 2 * (size_t)G3_ * H_ * 4      // wt0, wt1
                        + 2 * (size_t)B_ * H_ * 4       // h_state0, h_state1
                        + 1024;                          // alignment slack
    int Tc = 128, tcShift = 7;
    while (Tc > 1) {
        size_t need = fixedB
                    + 2 * (size_t)B_ * Tc * G3_ * 4     // gi0, gi1 chunks
                    + (size_t)B_ * Tc * H_ * 4;         // h1 chunk
        if (need <= ws_size) break;
        Tc >>= 1; tcShift--;
    }
    const int nChunks = T_ / Tc;

    char* ws = (char*)d_ws;
    size_t off = 0;
    auto alloc = [&](size_t bytes) { char* p = ws + off; off += (bytes + 255) & ~(size_t)255; return p; };
    float* gi0  = (float*)alloc((size_t)B_ * Tc * G3_ * 4);
    float* gi1  = (float*)alloc((size_t)B_ * Tc * G3_ * 4);
    float* h1c  = (float*)alloc((size_t)B_ * Tc * H_ * 4);
    float* wt0  = (float*)alloc((size_t)G3_ * H_ * 4);
    float* wt1  = (float*)alloc((size_t)G3_ * H_ * 4);
    float* hst0 = (float*)alloc((size_t)B_ * H_ * 4);
    float* hst1 = (float*)alloc((size_t)B_ * H_ * 4);

    k_transpose_whh<<<256, 256, 0, stream>>>(Whh0, wt0);
    k_transpose_whh<<<256, 256, 0, stream>>>(Whh1, wt1);

    const dim3 ggrid(G3_ / 64, (B_ * Tc) / 128);

    for (int c = 0; c < nChunks; ++c) {
        // layer 0 input gemm for this chunk: rows (b, c*Tc + tl)
        k_gemm_nt_bias<<<ggrid, 256, 0, stream>>>(
            x + (size_t)c * Tc * D_, (long)T_ * D_, Wih0, bih0, gi0,
            G3_, D_, tcShift);
        k_gru_scan_chunk<<<64, 256, 0, stream>>>(
            gi0, wt0, bhh0, hst0, h1c, Tc, c == 0);
        // layer 1 input gemm: h1c is chunk-major so b-stride = Tc*K
        k_gemm_nt_bias<<<ggrid, 256, 0, stream>>>(
            h1c, (long)Tc * H_, Wih1, bih1, gi1,
            G3_, H_, tcShift);
        k_gru_scan_chunk<<<64, 256, 0, stream>>>(
            gi1, wt1, bhh1, hst1, nullptr, Tc, c == 0);
    }

    k_fc<<<10, 256, 0, stream>>>(hst1, Wfc, bfc, out);
}